// Round 1
// baseline (487.159 us; speedup 1.0000x reference)
//
#include <hip/hip_runtime.h>
#include <math.h>

// AttentionLayer: D=1024, N=50000, fp32.
// Algebra: exp(a_w.X[0]) cancels in (alpha@X)/sum(alpha) -> a_alpha unused.
// Per module: b_w = b_alpha@W_alpha; one pass over X accumulating
// num = sum_j exp(X[j].b_w) X[j], den = sum_j exp(X[j].b_w);
// res = (num/den)@W_sum; out = elu(concat(res_in,res_out) @ lin_W^T + lin_b).

#define DD 1024
#define NROWS 50000
#define GB 512   // blocks per module in attn_pass (2 waves*... = 2048 waves/module)

// ---------------------------------------------------------------------------
// b_w[module][j] += sum_{i in chunk} v[i] * M[i*D+j]
// 128 blocks = 2 modules * 4 j-tiles * 16 i-chunks. Coalesced M reads,
// broadcast v reads, atomicAdd partials (out must be pre-zeroed).
__global__ __launch_bounds__(256) void vecmat_partial(
    const float* __restrict__ v0, const float* __restrict__ M0,
    const float* __restrict__ v1, const float* __restrict__ M1,
    float* __restrict__ out) {
  int bid = blockIdx.x;
  int module = bid >> 6;          // 64 blocks per module
  int r = bid & 63;
  int jb = r & 3;                 // j tile (4 * 256 = 1024 columns)
  int ic = r >> 2;                // i chunk (16 * 64 = 1024 rows)
  const float* __restrict__ v = module ? v1 : v0;
  const float* __restrict__ M = module ? M1 : M0;
  int j = jb * 256 + threadIdx.x;
  int i0 = ic * 64;
  float acc = 0.f;
#pragma unroll 4
  for (int i = i0; i < i0 + 64; ++i)
    acc = fmaf(v[i], M[i * DD + j], acc);
  atomicAdd(&out[module * DD + j], acc);
}

// ---------------------------------------------------------------------------
// Main pass: one wave per row. Lane l owns columns {q*256 + l*4 .. +3}, q<4.
// float4 loads are perfectly coalesced (64 lanes * 16B = 1KB contiguous/instr).
__global__ __launch_bounds__(256) void attn_pass(
    const float* __restrict__ X0, const float* __restrict__ X1,
    const float* __restrict__ bw_all,
    float* __restrict__ num0, float* __restrict__ den0,
    float* __restrict__ num1, float* __restrict__ den1) {
  int bid = blockIdx.x;
  int module = (bid >= GB) ? 1 : 0;
  int b = module ? bid - GB : bid;
  const float* __restrict__ X = module ? X1 : X0;
  float* __restrict__ num = module ? num1 : num0;
  float* __restrict__ den = module ? den1 : den0;
  const float* __restrict__ bw = bw_all + module * DD;

  int tid = threadIdx.x;
  int lane = tid & 63;
  int wave = tid >> 6;
  int w = b * 4 + wave;           // wave id within module
  const int WPM = GB * 4;         // waves per module

  float4 bwv[4], acc[4];
#pragma unroll
  for (int q = 0; q < 4; ++q) {
    bwv[q] = *reinterpret_cast<const float4*>(&bw[q * 256 + lane * 4]);
    acc[q] = make_float4(0.f, 0.f, 0.f, 0.f);
  }
  float asum = 0.f;

  for (int j = w; j < NROWS; j += WPM) {
    const float4* __restrict__ row =
        reinterpret_cast<const float4*>(X + (size_t)j * DD);
    float4 xv[4];
#pragma unroll
    for (int q = 0; q < 4; ++q) xv[q] = row[q * 64 + lane];
    float s = 0.f;
#pragma unroll
    for (int q = 0; q < 4; ++q) {
      s = fmaf(xv[q].x, bwv[q].x, s);
      s = fmaf(xv[q].y, bwv[q].y, s);
      s = fmaf(xv[q].z, bwv[q].z, s);
      s = fmaf(xv[q].w, bwv[q].w, s);
    }
    // wave64 butterfly all-reduce -> every lane holds full dot product
#pragma unroll
    for (int off = 32; off >= 1; off >>= 1) s += __shfl_xor(s, off, 64);
    float alpha = expf(s);
    asum += alpha;
#pragma unroll
    for (int q = 0; q < 4; ++q) {
      acc[q].x = fmaf(alpha, xv[q].x, acc[q].x);
      acc[q].y = fmaf(alpha, xv[q].y, acc[q].y);
      acc[q].z = fmaf(alpha, xv[q].z, acc[q].z);
      acc[q].w = fmaf(alpha, xv[q].w, acc[q].w);
    }
  }

  // block-level combine (4 waves) in LDS, then one atomicAdd per column/block
  __shared__ float sdata[4][DD];
  __shared__ float dsum[4];
#pragma unroll
  for (int q = 0; q < 4; ++q)
    *reinterpret_cast<float4*>(&sdata[wave][q * 256 + lane * 4]) = acc[q];
  if (lane == 0) dsum[wave] = asum;  // asum identical across lanes of a wave
  __syncthreads();

  float4 a0 = *reinterpret_cast<float4*>(&sdata[0][tid * 4]);
  float4 a1 = *reinterpret_cast<float4*>(&sdata[1][tid * 4]);
  float4 a2 = *reinterpret_cast<float4*>(&sdata[2][tid * 4]);
  float4 a3 = *reinterpret_cast<float4*>(&sdata[3][tid * 4]);
  int c = tid * 4;
  atomicAdd(&num[c + 0], a0.x + a1.x + a2.x + a3.x);
  atomicAdd(&num[c + 1], a0.y + a1.y + a2.y + a3.y);
  atomicAdd(&num[c + 2], a0.z + a1.z + a2.z + a3.z);
  atomicAdd(&num[c + 3], a0.w + a1.w + a2.w + a3.w);
  if (tid == 0) atomicAdd(den, dsum[0] + dsum[1] + dsum[2] + dsum[3]);
}

// ---------------------------------------------------------------------------
// out[k] = elu( sum_m res_raw[m]*inv_den(m) * lin_W[k*2048+m] + lin_b[k] )
__global__ __launch_bounds__(256) void final_kernel(
    const float* __restrict__ res_raw,
    const float* __restrict__ den0, const float* __restrict__ den1,
    const float* __restrict__ linW, const float* __restrict__ linb,
    float* __restrict__ out) {
  int k = blockIdx.x;
  int tid = threadIdx.x;
  float inv0 = 1.f / (*den0);
  float inv1 = 1.f / (*den1);
  const float* __restrict__ row = linW + (size_t)k * (2 * DD);
  float acc = 0.f;
#pragma unroll
  for (int s = 0; s < 8; ++s) {
    int m = s * 256 + tid;
    float attn = res_raw[m] * (m < DD ? inv0 : inv1);
    acc = fmaf(attn, row[m], acc);
  }
#pragma unroll
  for (int off = 32; off >= 1; off >>= 1) acc += __shfl_xor(acc, off, 64);
  __shared__ float wsum[4];
  int lane = tid & 63, wave = tid >> 6;
  if (lane == 0) wsum[wave] = acc;
  __syncthreads();
  if (tid == 0) {
    float v = wsum[0] + wsum[1] + wsum[2] + wsum[3] + linb[k];
    out[k] = v > 0.f ? v : expm1f(v);
  }
}

// ---------------------------------------------------------------------------
extern "C" void kernel_launch(void* const* d_in, const int* in_sizes, int n_in,
                              void* d_out, int out_size, void* d_ws, size_t ws_size,
                              hipStream_t stream) {
  const float* X_in    = (const float*)d_in[0];
  const float* X_out   = (const float*)d_in[1];
  const float* W_a_in  = (const float*)d_in[2];
  // d_in[3] = a_alpha_in  (unused: exp(a_w.X[0]) cancels in normalization)
  const float* b_a_in  = (const float*)d_in[4];
  const float* W_s_in  = (const float*)d_in[5];
  const float* W_a_out = (const float*)d_in[6];
  // d_in[7] = a_alpha_out (unused)
  const float* b_a_out = (const float*)d_in[8];
  const float* W_s_out = (const float*)d_in[9];
  const float* linW    = (const float*)d_in[10];
  const float* linb    = (const float*)d_in[11];
  float* out = (float*)d_out;
  float* ws  = (float*)d_ws;

  // workspace layout (floats):
  float* bw      = ws;            // [2*1024] b_w for both modules
  float* num0    = ws + 2048;     // [1024]
  float* den0    = ws + 3072;     // [1]
  float* num1    = ws + 3073;     // [1024]
  float* den1    = ws + 4097;     // [1]
  float* res_raw = ws + 4098;     // [2048] unnormalized res (den applied later)

  hipMemsetAsync(d_ws, 0, 6146 * sizeof(float), stream);
  vecmat_partial<<<128, 256, 0, stream>>>(b_a_in, W_a_in, b_a_out, W_a_out, bw);
  attn_pass<<<2 * GB, 256, 0, stream>>>(X_in, X_out, bw, num0, den0, num1, den1);
  vecmat_partial<<<128, 256, 0, stream>>>(num0, W_s_in, num1, W_s_out, res_raw);
  final_kernel<<<DD, 256, 0, stream>>>(res_raw, den0, den1, linW, linb, out);
}

// Round 2
// 447.686 us; speedup vs baseline: 1.0882x; 1.0882x over previous
//
#include <hip/hip_runtime.h>
#include <math.h>

// AttentionLayer: D=1024, N=50000, fp32.
// Algebra: exp(a_w.X[0]) cancels in (alpha@X)/sum(alpha) -> a_alpha unused.
// Per module: b_w = b_alpha@W_alpha; one pass over X accumulating
// num = sum_j exp(X[j].b_w) X[j], den = sum_j exp(X[j].b_w);
// res = (num/den)@W_sum; out = elu(concat(res_in,res_out) @ lin_W^T + lin_b).

#define DD 1024
#define NROWS 50000
#define GB 512     // blocks per module in attn_pass
#define RB 4       // rows per wave iteration (50000 % 4 == 0 -> no tail)
#define NPART 16   // partial accumulation buffers per module

// ---------------------------------------------------------------------------
// out[module*D+j] += sum_{i in chunk} v[i] * M[i*D+j]
// 256 blocks = 2 modules * 4 j-tiles * 32 i-chunks(32 rows). out pre-zeroed.
__global__ __launch_bounds__(256) void vecmat_partial(
    const float* __restrict__ v0, const float* __restrict__ M0,
    const float* __restrict__ v1, const float* __restrict__ M1,
    float* __restrict__ out) {
  int bid = blockIdx.x;
  int module = bid >> 7;          // 128 blocks per module
  int r = bid & 127;
  int jb = r & 3;                 // j tile (4 * 256 = 1024 columns)
  int ic = r >> 2;                // i chunk (32 * 32 = 1024 rows)
  const float* __restrict__ v = module ? v1 : v0;
  const float* __restrict__ M = module ? M1 : M0;
  int j = jb * 256 + threadIdx.x;
  int i0 = ic * 32;
  float acc = 0.f;
#pragma unroll 8
  for (int i = i0; i < i0 + 32; ++i)
    acc = fmaf(v[i], M[i * DD + j], acc);
  atomicAdd(&out[module * DD + j], acc);
}

// ---------------------------------------------------------------------------
// Main pass: one wave handles RB rows per iteration. Lane l owns columns
// {q*256 + l*4 .. +3}, q<4. All 16 float4 loads issue before one vmcnt wait;
// the 4 butterfly-reduce chains are independent and pipeline.
__global__ __launch_bounds__(256, 4) void attn_pass(
    const float* __restrict__ X0, const float* __restrict__ X1,
    const float* __restrict__ bw_all,
    float* __restrict__ num_part,   // [2][NPART][DD]
    float* __restrict__ den_part) { // [2][NPART]
  int bid = blockIdx.x;
  int module = (bid >= GB) ? 1 : 0;
  int b = module ? bid - GB : bid;
  const float* __restrict__ X = module ? X1 : X0;
  const float* __restrict__ bw = bw_all + module * DD;

  int tid = threadIdx.x;
  int lane = tid & 63;
  int wave = tid >> 6;
  int w = b * 4 + wave;           // wave id within module
  const int WPM = GB * 4;         // waves per module

  float4 bwv[4], acc[4];
#pragma unroll
  for (int q = 0; q < 4; ++q) {
    bwv[q] = *reinterpret_cast<const float4*>(&bw[q * 256 + lane * 4]);
    acc[q] = make_float4(0.f, 0.f, 0.f, 0.f);
  }
  float asum = 0.f;

  for (int j0 = w * RB; j0 < NROWS; j0 += WPM * RB) {
    float4 xv[RB][4];
#pragma unroll
    for (int r = 0; r < RB; ++r) {
      const float4* __restrict__ row =
          reinterpret_cast<const float4*>(X + (size_t)(j0 + r) * DD);
#pragma unroll
      for (int q = 0; q < 4; ++q) xv[r][q] = row[q * 64 + lane];
    }
    float s[RB];
#pragma unroll
    for (int r = 0; r < RB; ++r) {
      float t = 0.f;
#pragma unroll
      for (int q = 0; q < 4; ++q) {
        t = fmaf(xv[r][q].x, bwv[q].x, t);
        t = fmaf(xv[r][q].y, bwv[q].y, t);
        t = fmaf(xv[r][q].z, bwv[q].z, t);
        t = fmaf(xv[r][q].w, bwv[q].w, t);
      }
      s[r] = t;
    }
    // 4 independent wave64 butterfly all-reduces (latency pipelines)
#pragma unroll
    for (int off = 32; off >= 1; off >>= 1) {
#pragma unroll
      for (int r = 0; r < RB; ++r) s[r] += __shfl_xor(s[r], off, 64);
    }
#pragma unroll
    for (int r = 0; r < RB; ++r) {
      float alpha = __expf(s[r]);   // |s| ~ 0.05: native exp is exact enough
      asum += alpha;
#pragma unroll
      for (int q = 0; q < 4; ++q) {
        acc[q].x = fmaf(alpha, xv[r][q].x, acc[q].x);
        acc[q].y = fmaf(alpha, xv[r][q].y, acc[q].y);
        acc[q].z = fmaf(alpha, xv[r][q].z, acc[q].z);
        acc[q].w = fmaf(alpha, xv[r][q].w, acc[q].w);
      }
    }
  }

  // block-level combine (4 waves) in LDS, then atomicAdd into 1-of-16 partials
  __shared__ float sdata[4][DD];
  __shared__ float dsum[4];
#pragma unroll
  for (int q = 0; q < 4; ++q)
    *reinterpret_cast<float4*>(&sdata[wave][q * 256 + lane * 4]) = acc[q];
  if (lane == 0) dsum[wave] = asum;  // asum identical across lanes of a wave
  __syncthreads();

  float4 a0 = *reinterpret_cast<float4*>(&sdata[0][tid * 4]);
  float4 a1 = *reinterpret_cast<float4*>(&sdata[1][tid * 4]);
  float4 a2 = *reinterpret_cast<float4*>(&sdata[2][tid * 4]);
  float4 a3 = *reinterpret_cast<float4*>(&sdata[3][tid * 4]);
  int p = module * NPART + (b & (NPART - 1));
  float* __restrict__ np = num_part + (size_t)p * DD;
  int c = tid * 4;
  atomicAdd(&np[c + 0], a0.x + a1.x + a2.x + a3.x);
  atomicAdd(&np[c + 1], a0.y + a1.y + a2.y + a3.y);
  atomicAdd(&np[c + 2], a0.z + a1.z + a2.z + a3.z);
  atomicAdd(&np[c + 3], a0.w + a1.w + a2.w + a3.w);
  if (tid == 0) atomicAdd(&den_part[p], dsum[0] + dsum[1] + dsum[2] + dsum[3]);
}

// ---------------------------------------------------------------------------
// num[m][i] = sum_p num_part[m][p][i]; den[m] = sum_p den_part[m][p]
__global__ __launch_bounds__(256) void reduce_partials(
    const float* __restrict__ num_part, const float* __restrict__ den_part,
    float* __restrict__ num, float* __restrict__ den) {
  int idx = blockIdx.x * 256 + threadIdx.x;   // grid 8*256 = 2048
  int m = idx >> 10;
  int i = idx & (DD - 1);
  float s = 0.f;
#pragma unroll
  for (int p = 0; p < NPART; ++p)
    s += num_part[((size_t)(m * NPART + p)) * DD + i];
  num[idx] = s;
  if (idx < 2) {
    float d = 0.f;
#pragma unroll
    for (int p = 0; p < NPART; ++p) d += den_part[idx * NPART + p];
    den[idx] = d;
  }
}

// ---------------------------------------------------------------------------
// out[k] = elu( sum_m res_raw[m]*inv_den(m) * lin_W[k*2048+m] + lin_b[k] )
__global__ __launch_bounds__(256) void final_kernel(
    const float* __restrict__ res_raw, const float* __restrict__ den,
    const float* __restrict__ linW, const float* __restrict__ linb,
    float* __restrict__ out) {
  int k = blockIdx.x;
  int tid = threadIdx.x;
  float inv0 = 1.f / den[0];
  float inv1 = 1.f / den[1];
  const float* __restrict__ row = linW + (size_t)k * (2 * DD);
  float acc = 0.f;
#pragma unroll
  for (int s = 0; s < 8; ++s) {
    int m = s * 256 + tid;
    float attn = res_raw[m] * (m < DD ? inv0 : inv1);
    acc = fmaf(attn, row[m], acc);
  }
#pragma unroll
  for (int off = 32; off >= 1; off >>= 1) acc += __shfl_xor(acc, off, 64);
  __shared__ float wsum[4];
  int lane = tid & 63, wave = tid >> 6;
  if (lane == 0) wsum[wave] = acc;
  __syncthreads();
  if (tid == 0) {
    float v = wsum[0] + wsum[1] + wsum[2] + wsum[3] + linb[k];
    out[k] = v > 0.f ? v : expm1f(v);
  }
}

// ---------------------------------------------------------------------------
extern "C" void kernel_launch(void* const* d_in, const int* in_sizes, int n_in,
                              void* d_out, int out_size, void* d_ws, size_t ws_size,
                              hipStream_t stream) {
  const float* X_in    = (const float*)d_in[0];
  const float* X_out   = (const float*)d_in[1];
  const float* W_a_in  = (const float*)d_in[2];
  // d_in[3] = a_alpha_in  (unused: exp(a_w.X[0]) cancels in normalization)
  const float* b_a_in  = (const float*)d_in[4];
  const float* W_s_in  = (const float*)d_in[5];
  const float* W_a_out = (const float*)d_in[6];
  // d_in[7] = a_alpha_out (unused)
  const float* b_a_out = (const float*)d_in[8];
  const float* W_s_out = (const float*)d_in[9];
  const float* linW    = (const float*)d_in[10];
  const float* linb    = (const float*)d_in[11];
  float* out = (float*)d_out;
  float* ws  = (float*)d_ws;

  // workspace layout (floats):
  float* bw       = ws;              // [2*1024]
  float* num_part = ws + 2048;       // [2*16*1024] = 32768
  float* den_part = ws + 34816;      // [32]
  float* num      = ws + 34848;      // [2048]
  float* den      = ws + 36896;      // [2]
  float* res_raw  = ws + 36898;      // [2048]
  // total 38946 floats ~ 152 KB

  hipMemsetAsync(d_ws, 0, 38946 * sizeof(float), stream);
  vecmat_partial<<<256, 256, 0, stream>>>(b_a_in, W_a_in, b_a_out, W_a_out, bw);
  attn_pass<<<2 * GB, 256, 0, stream>>>(X_in, X_out, bw, num_part, den_part);
  reduce_partials<<<8, 256, 0, stream>>>(num_part, den_part, num, den);
  vecmat_partial<<<256, 256, 0, stream>>>(num, W_s_in, num + 1024, W_s_out, res_raw);
  final_kernel<<<DD, 256, 0, stream>>>(res_raw, den, linW, linb, out);
}